// Round 1
// baseline (1482.175 us; speedup 1.0000x reference)
//
#include <hip/hip_runtime.h>
#include <stdint.h>

#define BATCH 4
#define TDIM 256
#define NPIX 4096
#define START 63
#define PLEN 193          // TDIM - START
#define THRESH 0.9f
#define ROUNDS 16

typedef unsigned long long u64;

// ---------------------------------------------------------------------------
// Kernel 1: per-pixel MLP features + L2-normalize. Also init labels + flag.
// grid 64 x 256; pixel g = blockIdx*256+tid; coalesced over n (inner dim).
// ---------------------------------------------------------------------------
__global__ __launch_bounds__(256) void feat_kernel(
    const float* __restrict__ spike, const float* __restrict__ w1,
    const float* __restrict__ b1, const float* __restrict__ w2,
    const float* __restrict__ b2, float* __restrict__ fn,
    int* __restrict__ labA, int* __restrict__ flag)
{
    __shared__ float s_w1[PLEN * 16];
    __shared__ float s_b1[16];
    __shared__ float s_w2[16 * 8];
    __shared__ float s_b2[8];
    const int tid = threadIdx.x;
    for (int i = tid; i < PLEN * 16; i += 256) s_w1[i] = w1[i];
    if (tid < 16) s_b1[tid] = b1[tid];
    if (tid < 128) s_w2[tid] = w2[tid];
    if (tid < 8) s_b2[tid] = b2[tid];
    __syncthreads();

    const int g = blockIdx.x * 256 + tid;         // 0..16383
    const int b = g >> 12;
    const int n = g & (NPIX - 1);
    const float* sp = spike + ((size_t)b * TDIM + START) * NPIX + n;

    float h[16];
#pragma unroll
    for (int k = 0; k < 16; ++k) h[k] = 0.f;
    for (int t = 0; t < PLEN; ++t) {
        float x = sp[(size_t)t * NPIX];
#pragma unroll
        for (int k = 0; k < 16; ++k) h[k] = fmaf(x, s_w1[t * 16 + k], h[k]);
    }
#pragma unroll
    for (int k = 0; k < 16; ++k) {
        float z = h[k] + s_b1[k];
        h[k] = z / (1.f + expf(-z));              // silu
    }
    float f[8];
#pragma unroll
    for (int m = 0; m < 8; ++m) {
        float z = s_b2[m];
#pragma unroll
        for (int k = 0; k < 16; ++k) z = fmaf(h[k], s_w2[k * 8 + m], z);
        f[m] = z / (1.f + expf(-z));              // silu
    }
    float nrm = 0.f;
#pragma unroll
    for (int m = 0; m < 8; ++m) nrm = fmaf(f[m], f[m], nrm);
    nrm = fmaxf(sqrtf(nrm), 1e-6f);
#pragma unroll
    for (int m = 0; m < 8; ++m) f[m] = f[m] / nrm;

    float4* o4 = (float4*)(fn + (size_t)g * 8);
    o4[0] = make_float4(f[0], f[1], f[2], f[3]);
    o4[1] = make_float4(f[4], f[5], f[6], f[7]);

    labA[g] = n;                                   // identity labels (per batch)
    if (g == 0) *flag = 0;                         // convergence flag
}

// ---------------------------------------------------------------------------
// Kernel 2: adjacency bitmask. Block = 256 thr, handles batch b, 16 rows.
// fn_j staged in LDS in 1024-row chunks; __ballot builds 64-bit words.
// ---------------------------------------------------------------------------
__global__ __launch_bounds__(256) void adj_kernel(
    const float* __restrict__ fn, u64* __restrict__ adj)
{
    __shared__ float s_fj[1024 * 8];               // 32 KiB
    const int b  = blockIdx.x >> 8;
    const int i0 = (blockIdx.x & 255) << 4;
    const int tid = threadIdx.x;
    const int wave = tid >> 6, lane = tid & 63;
    const float* fnb = fn + (size_t)b * NPIX * 8;

    float fi[4][8];                                // 4 rows per wave
#pragma unroll
    for (int r = 0; r < 4; ++r) {
        const float* src = fnb + (size_t)(i0 + wave * 4 + r) * 8;
#pragma unroll
        for (int e = 0; e < 8; ++e) fi[r][e] = src[e];
    }
    u64 saved[4] = {0, 0, 0, 0};                   // word 'lane' of each row

    for (int jc = 0; jc < 4; ++jc) {
        __syncthreads();
        const float4* src4 = (const float4*)(fnb + (size_t)jc * 1024 * 8);
        float4* dst4 = (float4*)s_fj;
#pragma unroll
        for (int q = 0; q < 8; ++q) dst4[q * 256 + tid] = src4[q * 256 + tid];
        __syncthreads();

        for (int ww = 0; ww < 16; ++ww) {
            const int jl = ww * 64 + lane;
            const float4* pj = (const float4*)(s_fj + jl * 8);
            float4 a = pj[0], c = pj[1];
            float fj[8] = {a.x, a.y, a.z, a.w, c.x, c.y, c.z, c.w};
            const int widx = jc * 16 + ww;
#pragma unroll
            for (int r = 0; r < 4; ++r) {
                float d = 0.f;
#pragma unroll
                for (int e = 0; e < 8; ++e) d = fmaf(fj[e], fi[r][e], d);
                u64 mask = __ballot(d >= THRESH);
                if (lane == widx) saved[r] = mask;
            }
        }
    }
    u64* adjbase = adj + ((size_t)b * NPIX + i0) * 64;
#pragma unroll
    for (int r = 0; r < 4; ++r)
        adjbase[(size_t)(wave * 4 + r) * 64 + lane] = saved[r];
}

// ---------------------------------------------------------------------------
// Kernel 3: one propagation round. dst[i] = min over adj(i) of src[clamp(src[j])]
// (jump fused into gather). Early-exit via monotone flag; store flag=round+1
// when anything changed. 4 rows/block (1 per wave).
// ---------------------------------------------------------------------------
__global__ __launch_bounds__(256) void min_kernel(
    const u64* __restrict__ adj, const int* __restrict__ src,
    int* __restrict__ dst, int* __restrict__ flag, int round)
{
    if (round > 0) {
        int f = __hip_atomic_load(flag, __ATOMIC_RELAXED, __HIP_MEMORY_SCOPE_AGENT);
        if (f < round) return;                     // converged: labels final
    }
    const int wave = threadIdx.x >> 6, lane = threadIdx.x & 63;
    const int rowg = blockIdx.x * 4 + wave;        // 0..16383
    const int b = rowg >> 12, i = rowg & (NPIX - 1);
    const int* sb = src + (b << 12);
    const u64* arow = adj + (size_t)rowg * 64;
    const u64 myword = arow[lane];

    int mymin = NPIX;                              // reference uses N as +inf
#pragma unroll 4
    for (int w = 0; w < 64; ++w) {
        u64 word = __shfl(myword, w);
        if (word) {                                // wave-uniform skip
            int sj = sb[(w << 6) + lane];
            int lj = sb[min(sj, NPIX - 1)];        // fused pointer-jump (JAX clamp)
            if ((word >> lane) & 1ULL) mymin = min(mymin, lj);
        }
    }
#pragma unroll
    for (int off = 32; off > 0; off >>= 1)
        mymin = min(mymin, __shfl_xor(mymin, off));

    if (lane == 0) {
        dst[rowg] = mymin;
        if (mymin != sb[i])
            __hip_atomic_store(flag, round + 1, __ATOMIC_RELAXED,
                               __HIP_MEMORY_SCOPE_AGENT);
    }
}

// ---------------------------------------------------------------------------
// Kernel 4: final jump + is_root + cumsum rank + comp. One block per batch.
// ---------------------------------------------------------------------------
__global__ __launch_bounds__(256) void comp_kernel(
    const int* __restrict__ labsrc, int* __restrict__ comp)
{
    __shared__ int s_lab[NPIX];                    // 16 KiB
    __shared__ int s_rank[NPIX];                   // 16 KiB
    __shared__ int s_wsum[4];
    const int b = blockIdx.x, tid = threadIdx.x;
    const int* lb = labsrc + (b << 12);

    for (int i = tid; i < NPIX; i += 256) s_lab[i] = lb[i];
    __syncthreads();

    // final pointer-jump (matches reference: last op of each step is the jump)
    int regs[16];
#pragma unroll
    for (int k = 0; k < 16; ++k) {
        int i = k * 256 + tid;
        int v = s_lab[i];
        regs[k] = s_lab[min(v, NPIX - 1)];
    }
    __syncthreads();
#pragma unroll
    for (int k = 0; k < 16; ++k) s_lab[k * 256 + tid] = regs[k];
    __syncthreads();

    // inclusive cumsum of is_root, 16 contiguous elems per thread
    int loc[16];
    int sum = 0;
#pragma unroll
    for (int k = 0; k < 16; ++k) {
        int i = tid * 16 + k;
        sum += (s_lab[i] == i) ? 1 : 0;
        loc[k] = sum;
    }
    const int lane = tid & 63, wave = tid >> 6;
    int v = sum;
    for (int off = 1; off < 64; off <<= 1) {
        int u = __shfl_up(v, off);
        if (lane >= off) v += u;
    }
    if (lane == 63) s_wsum[wave] = v;
    __syncthreads();
    int waveoff = 0;
    for (int ww = 0; ww < 4; ++ww)
        if (ww < wave) waveoff += s_wsum[ww];
    const int excl = waveoff + v - sum;
#pragma unroll
    for (int k = 0; k < 16; ++k) s_rank[tid * 16 + k] = excl + loc[k] - 1;
    __syncthreads();

    int* cb = comp + (b << 12);
#pragma unroll
    for (int k = 0; k < 16; ++k) {
        int i = k * 256 + tid;
        cb[i] = s_rank[min(s_lab[i], NPIX - 1)];   // JAX clamp on rank[labels]
    }
}

// ---------------------------------------------------------------------------
// Kernel 5: write masks. out[b][r][p] = (comp[b][p] == r). float4 streams.
// ---------------------------------------------------------------------------
__global__ __launch_bounds__(256) void out_kernel(
    const int* __restrict__ comp, float4* __restrict__ out)
{
    const int lin = blockIdx.x * 256 + threadIdx.x; // 0..2^24-1
    const int p4 = lin & 1023;
    const int r  = (lin >> 10) & 4095;
    const int b  = lin >> 22;
    const int4 c = *(const int4*)(comp + (b << 12) + (p4 << 2));
    float4 vv;
    vv.x = (c.x == r) ? 1.f : 0.f;
    vv.y = (c.y == r) ? 1.f : 0.f;
    vv.z = (c.z == r) ? 1.f : 0.f;
    vv.w = (c.w == r) ? 1.f : 0.f;
    out[lin] = vv;
}

// ---------------------------------------------------------------------------
extern "C" void kernel_launch(void* const* d_in, const int* in_sizes, int n_in,
                              void* d_out, int out_size, void* d_ws, size_t ws_size,
                              hipStream_t stream)
{
    const float* spike = (const float*)d_in[0];
    const float* w1 = (const float*)d_in[1];
    const float* b1 = (const float*)d_in[2];
    const float* w2 = (const float*)d_in[3];
    const float* b2 = (const float*)d_in[4];

    // big scratch lives inside d_out (fully overwritten by out_kernel at end):
    //   [0, 8 MiB)          adjacency bitmask  (B*N rows x 64 u64 words)
    //   [8 MiB, 8.5 MiB)    fn features        (B*N x 8 f32)
    u64*   adj = (u64*)d_out;
    float* fn  = (float*)((char*)d_out + (size_t)8 * 1024 * 1024);
    // small state in d_ws (~196 KiB)
    int* labA = (int*)d_ws;
    int* labB = labA + BATCH * NPIX;
    int* comp = labB + BATCH * NPIX;
    int* flag = comp + BATCH * NPIX;

    feat_kernel<<<BATCH * NPIX / 256, 256, 0, stream>>>(spike, w1, b1, w2, b2,
                                                        fn, labA, flag);
    adj_kernel<<<BATCH * 256, 256, 0, stream>>>(fn, adj);

    int* bufs[2] = {labA, labB};
    for (int r = 0; r < ROUNDS; ++r)
        min_kernel<<<BATCH * NPIX / 4, 256, 0, stream>>>(adj, bufs[r & 1],
                                                         bufs[(r + 1) & 1], flag, r);

    comp_kernel<<<BATCH, 256, 0, stream>>>(bufs[ROUNDS & 1], comp);
    out_kernel<<<(BATCH * NPIX * NPIX / 4) / 256, 256, 0, stream>>>(
        comp, (float4*)d_out);
}

// Round 2
// 1372.025 us; speedup vs baseline: 1.0803x; 1.0803x over previous
//
#include <hip/hip_runtime.h>
#include <stdint.h>

#define BATCH 4
#define TDIM 256
#define NPIX 4096
#define START 63
#define PLEN 193          // TDIM - START
#define THRESH 0.9f
#define ROUNDS 16

typedef unsigned long long u64;

// ---------------------------------------------------------------------------
// Kernel 1: per-pixel MLP features + L2-normalize. Also init labels + flag.
// ---------------------------------------------------------------------------
__global__ __launch_bounds__(256) void feat_kernel(
    const float* __restrict__ spike, const float* __restrict__ w1,
    const float* __restrict__ b1, const float* __restrict__ w2,
    const float* __restrict__ b2, float* __restrict__ fn,
    int* __restrict__ labA, int* __restrict__ flag)
{
    __shared__ float s_w1[PLEN * 16];
    __shared__ float s_b1[16];
    __shared__ float s_w2[16 * 8];
    __shared__ float s_b2[8];
    const int tid = threadIdx.x;
    for (int i = tid; i < PLEN * 16; i += 256) s_w1[i] = w1[i];
    if (tid < 16) s_b1[tid] = b1[tid];
    if (tid < 128) s_w2[tid] = w2[tid];
    if (tid < 8) s_b2[tid] = b2[tid];
    __syncthreads();

    const int g = blockIdx.x * 256 + tid;         // 0..16383
    const int b = g >> 12;
    const int n = g & (NPIX - 1);
    const float* sp = spike + ((size_t)b * TDIM + START) * NPIX + n;

    float h[16];
#pragma unroll
    for (int k = 0; k < 16; ++k) h[k] = 0.f;
    for (int t = 0; t < PLEN; ++t) {
        float x = sp[(size_t)t * NPIX];
#pragma unroll
        for (int k = 0; k < 16; ++k) h[k] = fmaf(x, s_w1[t * 16 + k], h[k]);
    }
#pragma unroll
    for (int k = 0; k < 16; ++k) {
        float z = h[k] + s_b1[k];
        h[k] = z / (1.f + expf(-z));              // silu
    }
    float f[8];
#pragma unroll
    for (int m = 0; m < 8; ++m) {
        float z = s_b2[m];
#pragma unroll
        for (int k = 0; k < 16; ++k) z = fmaf(h[k], s_w2[k * 8 + m], z);
        f[m] = z / (1.f + expf(-z));              // silu
    }
    float nrm = 0.f;
#pragma unroll
    for (int m = 0; m < 8; ++m) nrm = fmaf(f[m], f[m], nrm);
    nrm = fmaxf(sqrtf(nrm), 1e-6f);
#pragma unroll
    for (int m = 0; m < 8; ++m) f[m] = f[m] / nrm;

    float4* o4 = (float4*)(fn + (size_t)g * 8);
    o4[0] = make_float4(f[0], f[1], f[2], f[3]);
    o4[1] = make_float4(f[4], f[5], f[6], f[7]);

    labA[g] = n;                                   // identity labels (per batch)
    if (g == 0) *flag = 0;                         // convergence flag
}

// ---------------------------------------------------------------------------
// Kernel 2: adjacency bitmask. Block = 256 thr, handles batch b, 16 rows.
// ---------------------------------------------------------------------------
__global__ __launch_bounds__(256) void adj_kernel(
    const float* __restrict__ fn, u64* __restrict__ adj)
{
    __shared__ float s_fj[1024 * 8];               // 32 KiB
    const int b  = blockIdx.x >> 8;
    const int i0 = (blockIdx.x & 255) << 4;
    const int tid = threadIdx.x;
    const int wave = tid >> 6, lane = tid & 63;
    const float* fnb = fn + (size_t)b * NPIX * 8;

    float fi[4][8];                                // 4 rows per wave
#pragma unroll
    for (int r = 0; r < 4; ++r) {
        const float* src = fnb + (size_t)(i0 + wave * 4 + r) * 8;
#pragma unroll
        for (int e = 0; e < 8; ++e) fi[r][e] = src[e];
    }
    u64 saved[4] = {0, 0, 0, 0};                   // word 'lane' of each row

    for (int jc = 0; jc < 4; ++jc) {
        __syncthreads();
        const float4* src4 = (const float4*)(fnb + (size_t)jc * 1024 * 8);
        float4* dst4 = (float4*)s_fj;
#pragma unroll
        for (int q = 0; q < 8; ++q) dst4[q * 256 + tid] = src4[q * 256 + tid];
        __syncthreads();

        for (int ww = 0; ww < 16; ++ww) {
            const int jl = ww * 64 + lane;
            const float4* pj = (const float4*)(s_fj + jl * 8);
            float4 a = pj[0], c = pj[1];
            float fj[8] = {a.x, a.y, a.z, a.w, c.x, c.y, c.z, c.w};
            const int widx = jc * 16 + ww;
#pragma unroll
            for (int r = 0; r < 4; ++r) {
                float d = 0.f;
#pragma unroll
                for (int e = 0; e < 8; ++e) d = fmaf(fj[e], fi[r][e], d);
                u64 mask = __ballot(d >= THRESH);
                if (lane == widx) saved[r] = mask;
            }
        }
    }
    u64* adjbase = adj + ((size_t)b * NPIX + i0) * 64;
#pragma unroll
    for (int r = 0; r < 4; ++r)
        adjbase[(size_t)(wave * 4 + r) * 64 + lane] = saved[r];
}

// ---------------------------------------------------------------------------
// Kernel 3a: jmp[g] = src[clamp(src[g])] — hoists the pointer-jump gather
// out of the min round so the min round has no dependent load chains.
// ---------------------------------------------------------------------------
__global__ __launch_bounds__(256) void jump_kernel(
    const int* __restrict__ src, int* __restrict__ jmp,
    const int* __restrict__ flag, int round)
{
    if (round > 0) {
        int f = __hip_atomic_load(flag, __ATOMIC_RELAXED, __HIP_MEMORY_SCOPE_AGENT);
        if (f < round) return;
    }
    const int g = blockIdx.x * 256 + threadIdx.x;  // 0..16383
    const int b = g >> 12;
    const int* sb = src + (b << 12);
    int v = sb[g & (NPIX - 1)];
    jmp[g] = sb[min(v, NPIX - 1)];                 // JAX OOB clamp
}

// ---------------------------------------------------------------------------
// Kernel 3b: one propagation round. dst[i] = min over adj(i) of jmp[j].
// Branch-free, coalesced, independent loads -> fully pipelined.
// 4 rows/block (1 per wave).
// ---------------------------------------------------------------------------
__global__ __launch_bounds__(256) void min_kernel(
    const u64* __restrict__ adj, const int* __restrict__ jmp,
    const int* __restrict__ src, int* __restrict__ dst,
    int* __restrict__ flag, int round)
{
    if (round > 0) {
        int f = __hip_atomic_load(flag, __ATOMIC_RELAXED, __HIP_MEMORY_SCOPE_AGENT);
        if (f < round) return;                     // converged: labels final
    }
    const int wave = threadIdx.x >> 6, lane = threadIdx.x & 63;
    const int rowg = blockIdx.x * 4 + wave;        // 0..16383
    const int b = rowg >> 12, i = rowg & (NPIX - 1);
    const int* jb = jmp + (b << 12);
    const u64* arow = adj + (size_t)rowg * 64;
    const u64 myword = arow[lane];

    int mymin = NPIX;                              // reference uses N as +inf
#pragma unroll 8
    for (int w = 0; w < 64; ++w) {
        int lj = jb[(w << 6) + lane];              // coalesced, L1-resident
        u64 word = __shfl(myword, w);
        mymin = min(mymin, ((word >> lane) & 1ULL) ? lj : NPIX);
    }
#pragma unroll
    for (int off = 32; off > 0; off >>= 1)
        mymin = min(mymin, __shfl_xor(mymin, off));

    if (lane == 0) {
        dst[rowg] = mymin;
        if (mymin != src[(b << 12) + i])
            __hip_atomic_store(flag, round + 1, __ATOMIC_RELAXED,
                               __HIP_MEMORY_SCOPE_AGENT);
    }
}

// ---------------------------------------------------------------------------
// Kernel 4: final jump + is_root + cumsum rank + comp. One block per batch.
// ---------------------------------------------------------------------------
__global__ __launch_bounds__(256) void comp_kernel(
    const int* __restrict__ labsrc, int* __restrict__ comp)
{
    __shared__ int s_lab[NPIX];                    // 16 KiB
    __shared__ int s_rank[NPIX];                   // 16 KiB
    __shared__ int s_wsum[4];
    const int b = blockIdx.x, tid = threadIdx.x;
    const int* lb = labsrc + (b << 12);

    for (int i = tid; i < NPIX; i += 256) s_lab[i] = lb[i];
    __syncthreads();

    // final pointer-jump (reference: last op of each step is the jump)
    int regs[16];
#pragma unroll
    for (int k = 0; k < 16; ++k) {
        int i = k * 256 + tid;
        int v = s_lab[i];
        regs[k] = s_lab[min(v, NPIX - 1)];
    }
    __syncthreads();
#pragma unroll
    for (int k = 0; k < 16; ++k) s_lab[k * 256 + tid] = regs[k];
    __syncthreads();

    // inclusive cumsum of is_root, 16 contiguous elems per thread
    int loc[16];
    int sum = 0;
#pragma unroll
    for (int k = 0; k < 16; ++k) {
        int i = tid * 16 + k;
        sum += (s_lab[i] == i) ? 1 : 0;
        loc[k] = sum;
    }
    const int lane = tid & 63, wave = tid >> 6;
    int v = sum;
    for (int off = 1; off < 64; off <<= 1) {
        int u = __shfl_up(v, off);
        if (lane >= off) v += u;
    }
    if (lane == 63) s_wsum[wave] = v;
    __syncthreads();
    int waveoff = 0;
    for (int ww = 0; ww < 4; ++ww)
        if (ww < wave) waveoff += s_wsum[ww];
    const int excl = waveoff + v - sum;
#pragma unroll
    for (int k = 0; k < 16; ++k) s_rank[tid * 16 + k] = excl + loc[k] - 1;
    __syncthreads();

    int* cb = comp + (b << 12);
#pragma unroll
    for (int k = 0; k < 16; ++k) {
        int i = k * 256 + tid;
        cb[i] = s_rank[min(s_lab[i], NPIX - 1)];   // JAX clamp on rank[labels]
    }
}

// ---------------------------------------------------------------------------
// Kernel 5: write masks. out[b][r][p] = (comp[b][p] == r). float4 streams.
// ---------------------------------------------------------------------------
__global__ __launch_bounds__(256) void out_kernel(
    const int* __restrict__ comp, float4* __restrict__ out)
{
    const int lin = blockIdx.x * 256 + threadIdx.x; // 0..2^24-1
    const int p4 = lin & 1023;
    const int r  = (lin >> 10) & 4095;
    const int b  = lin >> 22;
    const int4 c = *(const int4*)(comp + (b << 12) + (p4 << 2));
    float4 vv;
    vv.x = (c.x == r) ? 1.f : 0.f;
    vv.y = (c.y == r) ? 1.f : 0.f;
    vv.z = (c.z == r) ? 1.f : 0.f;
    vv.w = (c.w == r) ? 1.f : 0.f;
    out[lin] = vv;
}

// ---------------------------------------------------------------------------
extern "C" void kernel_launch(void* const* d_in, const int* in_sizes, int n_in,
                              void* d_out, int out_size, void* d_ws, size_t ws_size,
                              hipStream_t stream)
{
    const float* spike = (const float*)d_in[0];
    const float* w1 = (const float*)d_in[1];
    const float* b1 = (const float*)d_in[2];
    const float* w2 = (const float*)d_in[3];
    const float* b2 = (const float*)d_in[4];

    // big scratch lives inside d_out (fully overwritten by out_kernel at end):
    //   [0, 8 MiB)          adjacency bitmask  (B*N rows x 64 u64 words)
    //   [8 MiB, 8.5 MiB)    fn features        (B*N x 8 f32)
    u64*   adj = (u64*)d_out;
    float* fn  = (float*)((char*)d_out + (size_t)8 * 1024 * 1024);
    // small state in d_ws (~196 KiB)
    int* labA = (int*)d_ws;
    int* labB = labA + BATCH * NPIX;
    int* comp = labB + BATCH * NPIX;   // doubles as jmp during rounds
    int* flag = comp + BATCH * NPIX;

    feat_kernel<<<BATCH * NPIX / 256, 256, 0, stream>>>(spike, w1, b1, w2, b2,
                                                        fn, labA, flag);
    adj_kernel<<<BATCH * 256, 256, 0, stream>>>(fn, adj);

    int* bufs[2] = {labA, labB};
    for (int r = 0; r < ROUNDS; ++r) {
        jump_kernel<<<BATCH * NPIX / 256, 256, 0, stream>>>(bufs[r & 1], comp,
                                                            flag, r);
        min_kernel<<<BATCH * NPIX / 4, 256, 0, stream>>>(adj, comp, bufs[r & 1],
                                                         bufs[(r + 1) & 1], flag, r);
    }

    comp_kernel<<<BATCH, 256, 0, stream>>>(bufs[ROUNDS & 1], comp);
    out_kernel<<<(BATCH * NPIX * NPIX / 4) / 256, 256, 0, stream>>>(
        comp, (float4*)d_out);
}

// Round 3
// 281.921 us; speedup vs baseline: 5.2574x; 4.8667x over previous
//
#include <hip/hip_runtime.h>
#include <stdint.h>

#define BATCH 4
#define TDIM 256
#define NPIX 4096
#define START 63
#define PLEN 193          // TDIM - START
#define THRESH 0.9f
#define ROUNDS 16

typedef unsigned long long u64;
typedef unsigned int uint32;

// ---------------------------------------------------------------------------
// Kernel 1: per-pixel MLP features + L2-normalize. Also init labels + flag.
// ---------------------------------------------------------------------------
__global__ __launch_bounds__(256) void feat_kernel(
    const float* __restrict__ spike, const float* __restrict__ w1,
    const float* __restrict__ b1, const float* __restrict__ w2,
    const float* __restrict__ b2, float* __restrict__ fn,
    int* __restrict__ labA, int* __restrict__ flag)
{
    __shared__ float s_w1[PLEN * 16];
    __shared__ float s_b1[16];
    __shared__ float s_w2[16 * 8];
    __shared__ float s_b2[8];
    const int tid = threadIdx.x;
    for (int i = tid; i < PLEN * 16; i += 256) s_w1[i] = w1[i];
    if (tid < 16) s_b1[tid] = b1[tid];
    if (tid < 128) s_w2[tid] = w2[tid];
    if (tid < 8) s_b2[tid] = b2[tid];
    __syncthreads();

    const int g = blockIdx.x * 256 + tid;         // 0..16383
    const int b = g >> 12;
    const int n = g & (NPIX - 1);
    const float* sp = spike + ((size_t)b * TDIM + START) * NPIX + n;

    float h[16];
#pragma unroll
    for (int k = 0; k < 16; ++k) h[k] = 0.f;
    for (int t = 0; t < PLEN; ++t) {
        float x = sp[(size_t)t * NPIX];
#pragma unroll
        for (int k = 0; k < 16; ++k) h[k] = fmaf(x, s_w1[t * 16 + k], h[k]);
    }
#pragma unroll
    for (int k = 0; k < 16; ++k) {
        float z = h[k] + s_b1[k];
        h[k] = z / (1.f + expf(-z));              // silu
    }
    float f[8];
#pragma unroll
    for (int m = 0; m < 8; ++m) {
        float z = s_b2[m];
#pragma unroll
        for (int k = 0; k < 16; ++k) z = fmaf(h[k], s_w2[k * 8 + m], z);
        f[m] = z / (1.f + expf(-z));              // silu
    }
    float nrm = 0.f;
#pragma unroll
    for (int m = 0; m < 8; ++m) nrm = fmaf(f[m], f[m], nrm);
    nrm = fmaxf(sqrtf(nrm), 1e-6f);
#pragma unroll
    for (int m = 0; m < 8; ++m) f[m] = f[m] / nrm;

    float4* o4 = (float4*)(fn + (size_t)g * 8);
    o4[0] = make_float4(f[0], f[1], f[2], f[3]);
    o4[1] = make_float4(f[4], f[5], f[6], f[7]);

    labA[g] = n;                                   // identity labels (per batch)
    if (g == 0) *flag = 0;                         // convergence flag
}

// ---------------------------------------------------------------------------
// Kernel 2: adjacency bitmask. Block = 256 thr, handles batch b, 16 rows.
// ---------------------------------------------------------------------------
__global__ __launch_bounds__(256) void adj_kernel(
    const float* __restrict__ fn, u64* __restrict__ adj)
{
    __shared__ float s_fj[1024 * 8];               // 32 KiB
    const int b  = blockIdx.x >> 8;
    const int i0 = (blockIdx.x & 255) << 4;
    const int tid = threadIdx.x;
    const int wave = tid >> 6, lane = tid & 63;
    const float* fnb = fn + (size_t)b * NPIX * 8;

    float fi[4][8];                                // 4 rows per wave
#pragma unroll
    for (int r = 0; r < 4; ++r) {
        const float* src = fnb + (size_t)(i0 + wave * 4 + r) * 8;
#pragma unroll
        for (int e = 0; e < 8; ++e) fi[r][e] = src[e];
    }
    u64 saved[4] = {0, 0, 0, 0};                   // word 'lane' of each row

    for (int jc = 0; jc < 4; ++jc) {
        __syncthreads();
        const float4* src4 = (const float4*)(fnb + (size_t)jc * 1024 * 8);
        float4* dst4 = (float4*)s_fj;
#pragma unroll
        for (int q = 0; q < 8; ++q) dst4[q * 256 + tid] = src4[q * 256 + tid];
        __syncthreads();

        for (int ww = 0; ww < 16; ++ww) {
            const int jl = ww * 64 + lane;
            const float4* pj = (const float4*)(s_fj + jl * 8);
            float4 a = pj[0], c = pj[1];
            float fj[8] = {a.x, a.y, a.z, a.w, c.x, c.y, c.z, c.w};
            const int widx = jc * 16 + ww;
#pragma unroll
            for (int r = 0; r < 4; ++r) {
                float d = 0.f;
#pragma unroll
                for (int e = 0; e < 8; ++e) d = fmaf(fj[e], fi[r][e], d);
                u64 mask = __ballot(d >= THRESH);
                if (lane == widx) saved[r] = mask;
            }
        }
    }
    u64* adjbase = adj + ((size_t)b * NPIX + i0) * 64;
#pragma unroll
    for (int r = 0; r < 4; ++r)
        adjbase[(size_t)(wave * 4 + r) * 64 + lane] = saved[r];
}

// ---------------------------------------------------------------------------
// Kernel 3a: jmp[g] = src[clamp(src[g])] — pointer-jump hoisted out of the
// min round. Guard: skip once converged (plain load; kernel-boundary
// release/acquire provides visibility).
// ---------------------------------------------------------------------------
__global__ __launch_bounds__(256) void jump_kernel(
    const int* __restrict__ src, int* __restrict__ jmp,
    const int* __restrict__ flag, int round)
{
    if (round > 0 && flag[0] < round) return;
    const int g = blockIdx.x * 256 + threadIdx.x;  // 0..16383
    const int b = g >> 12;
    const int* sb = src + (b << 12);
    int v = sb[g & (NPIX - 1)];
    jmp[g] = sb[min(v, NPIX - 1)];                 // JAX OOB clamp
}

// ---------------------------------------------------------------------------
// Kernel 3b: one propagation round. dst[i] = min over adj(i) of jmp[j].
// jmp staged in LDS (one copy per block), adjacency words broadcast via
// readlane (uniform index -> no bpermute), 2 rows per wave, flag updated
// with ONE plain store per changed block (no same-address atomics).
// ---------------------------------------------------------------------------
__global__ __launch_bounds__(256) void min_kernel(
    const u64* __restrict__ adj, const int* __restrict__ jmp,
    const int* __restrict__ src, int* __restrict__ dst,
    int* __restrict__ flag, int round)
{
    if (round > 0 && flag[0] < round) return;      // converged: labels final
    __shared__ int s_jmp[NPIX];                    // 16 KiB
    __shared__ int s_chg;
    const int tid = threadIdx.x;
    if (tid == 0) s_chg = 0;
    const int wave = tid >> 6, lane = tid & 63;
    const int row0 = blockIdx.x * 8 + wave * 2;    // global row, 2 rows/wave
    const int b = row0 >> 12;

    const int4* g4 = (const int4*)(jmp + (b << 12));
    int4* s4 = (int4*)s_jmp;
#pragma unroll
    for (int q = 0; q < 4; ++q) s4[q * 256 + tid] = g4[q * 256 + tid];
    __syncthreads();

    const u64* arow = adj + (size_t)row0 * 64;
    const u64 wd0 = arow[lane];
    const u64 wd1 = arow[64 + lane];
    const uint32 lo0 = (uint32)wd0, hi0 = (uint32)(wd0 >> 32);
    const uint32 lo1 = (uint32)wd1, hi1 = (uint32)(wd1 >> 32);
    const uint32 lmask = 1u << (lane & 31);
    const bool hiHalf = lane >= 32;

    int m0 = NPIX, m1 = NPIX;                      // reference uses N as +inf
#pragma unroll 8
    for (int w = 0; w < 64; ++w) {
        const int lj = s_jmp[(w << 6) + lane];
        const uint32 ra0 = (uint32)__builtin_amdgcn_readlane((int)lo0, w);
        const uint32 rb0 = (uint32)__builtin_amdgcn_readlane((int)hi0, w);
        const uint32 ra1 = (uint32)__builtin_amdgcn_readlane((int)lo1, w);
        const uint32 rb1 = (uint32)__builtin_amdgcn_readlane((int)hi1, w);
        const uint32 h0 = hiHalf ? rb0 : ra0;
        const uint32 h1 = hiHalf ? rb1 : ra1;
        m0 = min(m0, (h0 & lmask) ? lj : NPIX);
        m1 = min(m1, (h1 & lmask) ? lj : NPIX);
    }
#pragma unroll
    for (int off = 32; off > 0; off >>= 1) {
        m0 = min(m0, __shfl_xor(m0, off));
        m1 = min(m1, __shfl_xor(m1, off));
    }

    if (lane == 0) {
        dst[row0] = m0;
        dst[row0 + 1] = m1;
        if (m0 != src[row0] || m1 != src[row0 + 1]) s_chg = 1;  // benign race
    }
    __syncthreads();
    if (tid == 0 && s_chg) *flag = round + 1;      // plain store, same value
}

// ---------------------------------------------------------------------------
// Kernel 4: final jump + is_root + cumsum rank + comp. One block per batch.
// ---------------------------------------------------------------------------
__global__ __launch_bounds__(256) void comp_kernel(
    const int* __restrict__ labsrc, int* __restrict__ comp)
{
    __shared__ int s_lab[NPIX];                    // 16 KiB
    __shared__ int s_rank[NPIX];                   // 16 KiB
    __shared__ int s_wsum[4];
    const int b = blockIdx.x, tid = threadIdx.x;
    const int* lb = labsrc + (b << 12);

    for (int i = tid; i < NPIX; i += 256) s_lab[i] = lb[i];
    __syncthreads();

    // final pointer-jump (reference: last op of each step is the jump)
    int regs[16];
#pragma unroll
    for (int k = 0; k < 16; ++k) {
        int i = k * 256 + tid;
        int v = s_lab[i];
        regs[k] = s_lab[min(v, NPIX - 1)];
    }
    __syncthreads();
#pragma unroll
    for (int k = 0; k < 16; ++k) s_lab[k * 256 + tid] = regs[k];
    __syncthreads();

    // inclusive cumsum of is_root, 16 contiguous elems per thread
    int loc[16];
    int sum = 0;
#pragma unroll
    for (int k = 0; k < 16; ++k) {
        int i = tid * 16 + k;
        sum += (s_lab[i] == i) ? 1 : 0;
        loc[k] = sum;
    }
    const int lane = tid & 63, wave = tid >> 6;
    int v = sum;
    for (int off = 1; off < 64; off <<= 1) {
        int u = __shfl_up(v, off);
        if (lane >= off) v += u;
    }
    if (lane == 63) s_wsum[wave] = v;
    __syncthreads();
    int waveoff = 0;
    for (int ww = 0; ww < 4; ++ww)
        if (ww < wave) waveoff += s_wsum[ww];
    const int excl = waveoff + v - sum;
#pragma unroll
    for (int k = 0; k < 16; ++k) s_rank[tid * 16 + k] = excl + loc[k] - 1;
    __syncthreads();

    int* cb = comp + (b << 12);
#pragma unroll
    for (int k = 0; k < 16; ++k) {
        int i = k * 256 + tid;
        cb[i] = s_rank[min(s_lab[i], NPIX - 1)];   // JAX clamp on rank[labels]
    }
}

// ---------------------------------------------------------------------------
// Kernel 5: write masks. out[b][r][p] = (comp[b][p] == r). float4 streams.
// ---------------------------------------------------------------------------
__global__ __launch_bounds__(256) void out_kernel(
    const int* __restrict__ comp, float4* __restrict__ out)
{
    const int lin = blockIdx.x * 256 + threadIdx.x; // 0..2^24-1
    const int p4 = lin & 1023;
    const int r  = (lin >> 10) & 4095;
    const int b  = lin >> 22;
    const int4 c = *(const int4*)(comp + (b << 12) + (p4 << 2));
    float4 vv;
    vv.x = (c.x == r) ? 1.f : 0.f;
    vv.y = (c.y == r) ? 1.f : 0.f;
    vv.z = (c.z == r) ? 1.f : 0.f;
    vv.w = (c.w == r) ? 1.f : 0.f;
    out[lin] = vv;
}

// ---------------------------------------------------------------------------
extern "C" void kernel_launch(void* const* d_in, const int* in_sizes, int n_in,
                              void* d_out, int out_size, void* d_ws, size_t ws_size,
                              hipStream_t stream)
{
    const float* spike = (const float*)d_in[0];
    const float* w1 = (const float*)d_in[1];
    const float* b1 = (const float*)d_in[2];
    const float* w2 = (const float*)d_in[3];
    const float* b2 = (const float*)d_in[4];

    // big scratch lives inside d_out (fully overwritten by out_kernel at end):
    //   [0, 8 MiB)          adjacency bitmask  (B*N rows x 64 u64 words)
    //   [8 MiB, 8.5 MiB)    fn features        (B*N x 8 f32)
    u64*   adj = (u64*)d_out;
    float* fn  = (float*)((char*)d_out + (size_t)8 * 1024 * 1024);
    // small state in d_ws (~196 KiB)
    int* labA = (int*)d_ws;
    int* labB = labA + BATCH * NPIX;
    int* comp = labB + BATCH * NPIX;   // doubles as jmp during rounds
    int* flag = comp + BATCH * NPIX;

    feat_kernel<<<BATCH * NPIX / 256, 256, 0, stream>>>(spike, w1, b1, w2, b2,
                                                        fn, labA, flag);
    adj_kernel<<<BATCH * 256, 256, 0, stream>>>(fn, adj);

    int* bufs[2] = {labA, labB};
    for (int r = 0; r < ROUNDS; ++r) {
        jump_kernel<<<BATCH * NPIX / 256, 256, 0, stream>>>(bufs[r & 1], comp,
                                                            flag, r);
        min_kernel<<<BATCH * NPIX / 8, 256, 0, stream>>>(adj, comp, bufs[r & 1],
                                                         bufs[(r + 1) & 1], flag, r);
    }

    comp_kernel<<<BATCH, 256, 0, stream>>>(bufs[ROUNDS & 1], comp);
    out_kernel<<<(BATCH * NPIX * NPIX / 4) / 256, 256, 0, stream>>>(
        comp, (float4*)d_out);
}